// Round 10
// baseline (518.148 us; speedup 1.0000x reference)
//
#include <hip/hip_runtime.h>
#include <math.h>

typedef unsigned short u16;
typedef short s16x8 __attribute__((ext_vector_type(8)));  // 8 bf16 lanes (4 VGPRs)
typedef float f32x4 __attribute__((ext_vector_type(4)));

// B=2, S=2048, D=2048, H=16, HD=128; qkv row width = 6144
#define ATTN_SCALE 0.08838834764831845f
#define NEG_BIG -1.0e30f

__device__ __forceinline__ u16 f2bf(float f) {
  union { float f; unsigned u; } c; c.f = f;
  return (u16)((c.u + 0x7fffu + ((c.u >> 16) & 1u)) >> 16);  // RNE
}
__device__ __forceinline__ float bf2f(u16 v) {
  union { unsigned u; float f; } c; c.u = ((unsigned)v) << 16;
  return c.f;
}
__device__ __forceinline__ f32x4 mfma16(s16x8 a, s16x8 b, f32x4 c) {
  return __builtin_amdgcn_mfma_f32_16x16x32_bf16(a, b, c, 0, 0, 0);
}
// async global->LDS DMA, 16 B/lane; LDS dest = wave-uniform base + lane*16
__device__ __forceinline__ void gl_lds16(const u16* g, u16* l) {
  __builtin_amdgcn_global_load_lds(
      (const __attribute__((address_space(1))) unsigned int*)g,
      (__attribute__((address_space(3))) unsigned int*)l, 16, 0, 0);
}

// -------- fp32 -> bf16 elementwise cast (float4 vectorized) -------------
__global__ __launch_bounds__(256) void k_cast(const float* __restrict__ in,
                                              u16* __restrict__ out, int n4) {
  const int i = blockIdx.x * 256 + threadIdx.x;
  if (i >= n4) return;
  const float4 v = ((const float4*)in)[i];
  ushort4 o;
  o.x = f2bf(v.x); o.y = f2bf(v.y); o.z = f2bf(v.z); o.w = f2bf(v.w);
  ((ushort4*)out)[i] = o;
}

// -------- fp32 [R][C] -> bf16 out[C][R] transpose+cast ------------------
__global__ __launch_bounds__(256) void k_transpose_cast(const float* __restrict__ in,
                                                        u16* __restrict__ out,
                                                        int R, int C) {
  __shared__ __attribute__((aligned(16))) u16 tile[32][33];
  const int c0 = blockIdx.x * 32, r0 = blockIdx.y * 32;
  const int tx = threadIdx.x, ty = threadIdx.y;
#pragma unroll
  for (int i = 0; i < 4; ++i)
    tile[ty + 8 * i][tx] = f2bf(in[(r0 + ty + 8 * i) * C + c0 + tx]);
  __syncthreads();
#pragma unroll
  for (int i = 0; i < 4; ++i)
    out[(c0 + ty + 8 * i) * R + r0 + tx] = tile[tx][ty + 8 * i];
}

// ---------------- V -> V^T per (b,h): vt[bh][d][s] = qkv_v[b,s,h,d] ------
__global__ __launch_bounds__(256) void k_vtrans(const u16* __restrict__ qkv,
                                                u16* __restrict__ vt) {
  __shared__ __attribute__((aligned(16))) u16 tile[32][33];
  const int bh = blockIdx.z, b = bh >> 4, h = bh & 15;
  const int s0 = blockIdx.x * 32, d0 = blockIdx.y * 32;
  const int tx = threadIdx.x, ty = threadIdx.y;
#pragma unroll
  for (int i = 0; i < 4; ++i) {
    const int s = s0 + ty + 8 * i;
    tile[ty + 8 * i][tx] = qkv[(b * 2048 + s) * 6144 + 4096 + h * 128 + d0 + tx];
  }
  __syncthreads();
#pragma unroll
  for (int i = 0; i < 4; ++i) {
    const int d = d0 + ty + 8 * i;
    vt[bh * 262144 + d * 2048 + s0 + tx] = tile[tx][ty + 8 * i];
  }
}

// ---------------- RoPE in-place on Q and K sections of qkv (bf16) -------
__global__ __launch_bounds__(256) void k_rope(u16* __restrict__ qkv) {
  const int id = blockIdx.x * 256 + threadIdx.x;  // 8,388,608 threads
  const int j = id & 63;
  const int h = (id >> 6) & 15;
  const int sec = (id >> 10) & 1;
  const int m = id >> 11;  // b*2048+s
  const int s = m & 2047;
  const int base = m * 6144 + sec * 2048 + h * 128 + j;
  const float q0 = bf2f(qkv[base]);
  const float q1 = bf2f(qkv[base + 64]);
  const float inv = exp2f((float)j * -0.20762050593046014f);  // 10000^(-j/64)
  const float ang = (float)s * inv;
  float c, sn;
  sincosf(ang, &sn, &c);  // sincosf(x, SIN*, COS*) — sin FIRST
  qkv[base]      = f2bf(q0 * c - q1 * sn);
  qkv[base + 64] = f2bf(q1 * c + q0 * sn);
}

// ------- GEMM (m97 structure): C[M][N] = A[M][K] * BT[N][K]^T -----------
template <bool A_F32, typename OUT_T>
__global__ __launch_bounds__(256) void k_gemm_lds(const void* __restrict__ Ap, int lda,
                                                  const u16* __restrict__ BT,
                                                  OUT_T* __restrict__ C, int ldc,
                                                  int K) {
  __shared__ __attribute__((aligned(16))) u16 As[128 * 32];
  __shared__ __attribute__((aligned(16))) u16 Bs[128 * 32];
  const int tid = threadIdx.x;
  const int lane = tid & 63, wave = tid >> 6;
  const int lm = lane & 15, quad = lane >> 4;
  const int wm = wave >> 1, wn = wave & 1;
  const int m0 = blockIdx.y * 128, n0 = blockIdx.x * 128;
  const int srow = lane >> 2, scol = (lane & 3) * 8;  // staging map

  const f32x4 fzero = {0.f, 0.f, 0.f, 0.f};
  f32x4 acc[4][4];
#pragma unroll
  for (int i = 0; i < 4; ++i)
#pragma unroll
    for (int j = 0; j < 4; ++j) acc[i][j] = fzero;

  for (int k0 = 0; k0 < K; k0 += 32) {
    __syncthreads();
    if constexpr (A_F32) {
      const float* Af = (const float*)Ap;
#pragma unroll
      for (int i = 0; i < 2; ++i) {
        const int seg = tid + 256 * i;
        const int row = seg >> 2, c8 = (seg & 3) * 8;
        const float4 u = *(const float4*)&Af[(m0 + row) * lda + k0 + c8];
        const float4 w = *(const float4*)&Af[(m0 + row) * lda + k0 + c8 + 4];
        uint4 pk;
        pk.x = (unsigned)f2bf(u.x) | ((unsigned)f2bf(u.y) << 16);
        pk.y = (unsigned)f2bf(u.z) | ((unsigned)f2bf(u.w) << 16);
        pk.z = (unsigned)f2bf(w.x) | ((unsigned)f2bf(w.y) << 16);
        pk.w = (unsigned)f2bf(w.z) | ((unsigned)f2bf(w.w) << 16);
        *(uint4*)&As[row * 32 + c8] = pk;
      }
#pragma unroll
      for (int j = 0; j < 2; ++j) {
        const int rb = wave * 32 + j * 16;
        gl_lds16(&BT[(n0 + rb + srow) * K + k0 + scol], &Bs[rb * 32]);
      }
    } else {
      const u16* Ab = (const u16*)Ap;
#pragma unroll
      for (int j = 0; j < 2; ++j) {
        const int rb = wave * 32 + j * 16;
        gl_lds16(&Ab[(m0 + rb + srow) * lda + k0 + scol], &As[rb * 32]);
        gl_lds16(&BT[(n0 + rb + srow) * K + k0 + scol], &Bs[rb * 32]);
      }
    }
    __syncthreads();  // drains vmcnt (DMA) + lgkmcnt before reads

    s16x8 af[4], bfr[4];
#pragma unroll
    for (int t = 0; t < 4; ++t) {
      af[t]  = *(const s16x8*)&As[(wm * 64 + t * 16 + lm) * 32 + quad * 8];
      bfr[t] = *(const s16x8*)&Bs[(wn * 64 + t * 16 + lm) * 32 + quad * 8];
    }
#pragma unroll
    for (int mt = 0; mt < 4; ++mt)
#pragma unroll
      for (int nt = 0; nt < 4; ++nt)
        acc[mt][nt] = mfma16(af[mt], bfr[nt], acc[mt][nt]);
  }
#pragma unroll
  for (int mt = 0; mt < 4; ++mt)
#pragma unroll
    for (int nt = 0; nt < 4; ++nt)
#pragma unroll
      for (int r = 0; r < 4; ++r) {
        const float v = acc[mt][nt][r];
        const int idx = (m0 + wm * 64 + mt * 16 + quad * 4 + r) * ldc +
                        n0 + wn * 64 + nt * 16 + lm;
        if constexpr (sizeof(OUT_T) == 2) C[idx] = f2bf(v);
        else                              C[idx] = v;
      }
}

// ---------------- causal flash attention, v3 ----------------------------
// 64-key tiles, causal pairing {pair, 31-pair} (33 iters/block, uniform),
// SOFTWARE-PIPELINED double-buffered K/V staging (1 barrier/iter; next
// tile's global loads issue before current tile's compute), XCD-swizzled
// grid (blockIdx.x = bh -> all pair-blocks of a head share an XCD's L2).
__global__ __launch_bounds__(256) void k_attn(u16* __restrict__ qkv,
                                              const u16* __restrict__ vt) {
  __shared__ __attribute__((aligned(16))) u16 Ks[2][64 * 136];   // 2x17408 B
  __shared__ __attribute__((aligned(16))) u16 Vs[2][128 * 72];   // 2x18432 B
  __shared__ __attribute__((aligned(16))) u16 Ps[4 * 16 * 72];   //   9216 B
  const int bh = blockIdx.x, pair = blockIdx.y;
  const int b = bh >> 4, h = bh & 15;
  const int tid = threadIdx.x;
  const int lane = tid & 63, wave = tid >> 6;
  const int lm = lane & 15, quad = lane >> 4;
  const int pbase = wave * 1152;
  const f32x4 fzero = {0.f, 0.f, 0.f, 0.f};

  // iteration schedule: it 0..pair -> (qtile=pair, kt=it);
  //                     it pair+1..32 -> (qtile=31-pair, kt=it-pair-1)
  const int phase_end = pair;

  // per-thread staging registers (next tile)
  uint4 kr[4], vr[4];
  auto load_tile = [&](int kt0) {
#pragma unroll
    for (int i = 0; i < 4; ++i) {
      const int seg = tid + 256 * i;
      {
        const int row = seg >> 4, c8 = (seg & 15) * 8;
        kr[i] = *(const uint4*)&qkv[(b * 2048 + kt0 + row) * 6144 + 2048 + h * 128 + c8];
      }
      {
        const int row = seg >> 3, c8 = (seg & 7) * 8;
        vr[i] = *(const uint4*)&vt[bh * 262144 + row * 2048 + kt0 + c8];
      }
    }
  };
  auto store_tile = [&](int buf) {
#pragma unroll
    for (int i = 0; i < 4; ++i) {
      const int seg = tid + 256 * i;
      {
        const int row = seg >> 4, c8 = (seg & 15) * 8;
        *(uint4*)&Ks[buf][row * 136 + c8] = kr[i];
      }
      {
        const int row = seg >> 3, c8 = (seg & 7) * 8;
        *(uint4*)&Vs[buf][row * 72 + c8] = vr[i];
      }
    }
  };

  // ---- prologue: stage tile for it=0 (kt=0) into buf 0 ----
  load_tile(0);
  store_tile(0);

  // ---- phase-0 state (qtile = pair) ----
  int qtile = pair;
  int qb = qtile * 64;
  int qrow = qb + wave * 16 + lm;
  int qoff = (b * 2048 + qrow) * 6144 + h * 128;
  s16x8 qfrag[4];
#pragma unroll
  for (int c = 0; c < 4; ++c)
    qfrag[c] = *(const s16x8*)&qkv[qoff + c * 32 + quad * 8];
  f32x4 o[8];
#pragma unroll
  for (int dt = 0; dt < 8; ++dt) o[dt] = fzero;
  float m_run = NEG_BIG, l_run = 0.f;

  __syncthreads();  // buf0 staged

  for (int it = 0; it < 33; ++it) {
    const int kt0 = (it <= phase_end ? it : it - phase_end - 1) * 64;
    const int buf = it & 1;

    // issue next tile's global loads (latency hidden behind compute)
    if (it < 32) {
      const int nkt = (it + 1 <= phase_end ? it + 1 : it - phase_end) * 64;
      load_tile(nkt);
    }

    // ---- compute on buf ----
    f32x4 sa[4];
#pragma unroll
    for (int ss = 0; ss < 4; ++ss) sa[ss] = fzero;
#pragma unroll
    for (int ss = 0; ss < 4; ++ss)
#pragma unroll
      for (int c = 0; c < 4; ++c) {
        s16x8 a = *(const s16x8*)&Ks[buf][(ss * 16 + lm) * 136 + c * 32 + quad * 8];
        sa[ss] = mfma16(a, qfrag[c], sa[ss]);
      }

    float p[4][4];
    float vmax = NEG_BIG;
#pragma unroll
    for (int ss = 0; ss < 4; ++ss)
#pragma unroll
      for (int r = 0; r < 4; ++r) {
        const int kg = kt0 + ss * 16 + quad * 4 + r;
        float v = sa[ss][r] * ATTN_SCALE;
        if (kg > qrow) v = NEG_BIG;
        p[ss][r] = v;
        vmax = fmaxf(vmax, v);
      }
    vmax = fmaxf(vmax, __shfl_xor(vmax, 16, 64));
    vmax = fmaxf(vmax, __shfl_xor(vmax, 32, 64));
    const float m_new = fmaxf(m_run, vmax);
    const float alpha = __expf(m_run - m_new);
    float rsum = 0.f;
#pragma unroll
    for (int ss = 0; ss < 4; ++ss)
#pragma unroll
      for (int r = 0; r < 4; ++r) {
        p[ss][r] = __expf(p[ss][r] - m_new);  // masked: exp(-huge) = 0
        rsum += p[ss][r];
      }
    rsum += __shfl_xor(rsum, 16, 64);
    rsum += __shfl_xor(rsum, 32, 64);
    l_run = l_run * alpha + rsum;
    m_run = m_new;
#pragma unroll
    for (int dt = 0; dt < 8; ++dt) o[dt] *= alpha;

    // P -> wave-private LDS (intra-wave ordering; no barrier)
#pragma unroll
    for (int ss = 0; ss < 4; ++ss)
#pragma unroll
      for (int r = 0; r < 4; ++r)
        Ps[pbase + lm * 72 + ss * 16 + quad * 4 + r] = f2bf(p[ss][r]);
    const s16x8 pv0 = *(const s16x8*)&Ps[pbase + lm * 72 + quad * 8];
    const s16x8 pv1 = *(const s16x8*)&Ps[pbase + lm * 72 + 32 + quad * 8];

#pragma unroll
    for (int dt = 0; dt < 8; ++dt) {
      s16x8 a0 = *(const s16x8*)&Vs[buf][(dt * 16 + lm) * 72 + quad * 8];
      s16x8 a1 = *(const s16x8*)&Vs[buf][(dt * 16 + lm) * 72 + 32 + quad * 8];
      o[dt] = mfma16(a1, pv1, mfma16(a0, pv0, o[dt]));
    }

    // ---- phase boundary: write phase-0 output, reset for phase 1 ----
    if (it == phase_end) {
      const float inv_l = 1.0f / l_run;
#pragma unroll
      for (int dt = 0; dt < 8; ++dt)
#pragma unroll
        for (int r = 0; r < 4; ++r)
          qkv[qoff + dt * 16 + quad * 4 + r] = f2bf(o[dt][r] * inv_l);
      qtile = 31 - pair;
      qb = qtile * 64;
      qrow = qb + wave * 16 + lm;
      qoff = (b * 2048 + qrow) * 6144 + h * 128;
#pragma unroll
      for (int c = 0; c < 4; ++c)
        qfrag[c] = *(const s16x8*)&qkv[qoff + c * 32 + quad * 8];
#pragma unroll
      for (int dt = 0; dt < 8; ++dt) o[dt] = fzero;
      m_run = NEG_BIG; l_run = 0.f;
    }

    // ---- stage next tile into the other buffer; single barrier ----
    if (it < 32) {
      store_tile(buf ^ 1);
      __syncthreads();
    }
  }

  // ---- phase-1 epilogue ----
  const float inv_l = 1.0f / l_run;
#pragma unroll
  for (int dt = 0; dt < 8; ++dt)
#pragma unroll
    for (int r = 0; r < 4; ++r)
      qkv[qoff + dt * 16 + quad * 4 + r] = f2bf(o[dt][r] * inv_l);
}

// ---------------- host launcher ----------------------------------------
extern "C" void kernel_launch(void* const* d_in, const int* in_sizes, int n_in,
                              void* d_out, int out_size, void* d_ws, size_t ws_size,
                              hipStream_t stream) {
  const float* hidden = (const float*)d_in[0];  // [4096][2048] fp32
  const float* w_qkv  = (const float*)d_in[1];  // [2048][6144] fp32
  const float* w_o    = (const float*)d_in[2];  // [2048][2048] fp32
  float* out = (float*)d_out;                   // [4096][2048] fp32
  u16* ws = (u16*)d_ws;

  u16* qkv   = ws;
  u16* wqkvT = ws + 25165824;
  u16* vt    = ws + 25165824;
  u16* woT   = ws + 33554432;
  u16* hb    = ws + 37748736;
  const bool fast = ws_size >= (size_t)46137344 * 2;

  dim3 tb(32, 8);
  k_transpose_cast<<<dim3(192, 64), tb, 0, stream>>>(w_qkv, wqkvT, 2048, 6144);
  if (fast) {
    k_cast<<<8192, 256, 0, stream>>>(hidden, hb, 2097152);
    k_gemm_lds<false, u16><<<dim3(48, 32), 256, 0, stream>>>(hb, 2048, wqkvT,
                                                             qkv, 6144, 2048);
  } else {
    k_gemm_lds<true, u16><<<dim3(48, 32), 256, 0, stream>>>(hidden, 2048, wqkvT,
                                                            qkv, 6144, 2048);
  }
  k_rope<<<32768, 256, 0, stream>>>(qkv);
  k_vtrans<<<dim3(64, 4, 32), tb, 0, stream>>>(qkv, vt);
  k_transpose_cast<<<dim3(64, 64), tb, 0, stream>>>(w_o, woT, 2048, 2048);
  k_attn<<<dim3(32, 16), 256, 0, stream>>>(qkv, vt);  // x=bh (XCD locality)
  k_gemm_lds<false, float><<<dim3(16, 32), 256, 0, stream>>>(qkv, 6144, woT,
                                                             out, 2048, 2048);
}

// Round 11
// 422.424 us; speedup vs baseline: 1.2266x; 1.2266x over previous
//
#include <hip/hip_runtime.h>
#include <math.h>

typedef unsigned short u16;
typedef short s16x8 __attribute__((ext_vector_type(8)));  // 8 bf16 lanes (4 VGPRs)
typedef float f32x4 __attribute__((ext_vector_type(4)));

// B=2, S=2048, D=2048, H=16, HD=128; qkv row width = 6144
#define ATTN_SCALE 0.08838834764831845f
#define NEG_BIG -1.0e30f

__device__ __forceinline__ u16 f2bf(float f) {
  union { float f; unsigned u; } c; c.f = f;
  return (u16)((c.u + 0x7fffu + ((c.u >> 16) & 1u)) >> 16);  // RNE
}
__device__ __forceinline__ float bf2f(u16 v) {
  union { unsigned u; float f; } c; c.u = ((unsigned)v) << 16;
  return c.f;
}
__device__ __forceinline__ f32x4 mfma16(s16x8 a, s16x8 b, f32x4 c) {
  return __builtin_amdgcn_mfma_f32_16x16x32_bf16(a, b, c, 0, 0, 0);
}
// async global->LDS DMA, 16 B/lane; LDS dest = wave-uniform base + lane*16
__device__ __forceinline__ void gl_lds16(const u16* g, u16* l) {
  __builtin_amdgcn_global_load_lds(
      (const __attribute__((address_space(1))) unsigned int*)g,
      (__attribute__((address_space(3))) unsigned int*)l, 16, 0, 0);
}

// -------- fp32 -> bf16 elementwise cast (float4 vectorized) -------------
__global__ __launch_bounds__(256) void k_cast(const float* __restrict__ in,
                                              u16* __restrict__ out, int n4) {
  const int i = blockIdx.x * 256 + threadIdx.x;
  if (i >= n4) return;
  const float4 v = ((const float4*)in)[i];
  ushort4 o;
  o.x = f2bf(v.x); o.y = f2bf(v.y); o.z = f2bf(v.z); o.w = f2bf(v.w);
  ((ushort4*)out)[i] = o;
}

// -------- fp32 [R][C] -> bf16 out[C][R] transpose+cast ------------------
__global__ __launch_bounds__(256) void k_transpose_cast(const float* __restrict__ in,
                                                        u16* __restrict__ out,
                                                        int R, int C) {
  __shared__ __attribute__((aligned(16))) u16 tile[32][33];
  const int c0 = blockIdx.x * 32, r0 = blockIdx.y * 32;
  const int tx = threadIdx.x, ty = threadIdx.y;
#pragma unroll
  for (int i = 0; i < 4; ++i)
    tile[ty + 8 * i][tx] = f2bf(in[(r0 + ty + 8 * i) * C + c0 + tx]);
  __syncthreads();
#pragma unroll
  for (int i = 0; i < 4; ++i)
    out[(c0 + ty + 8 * i) * R + r0 + tx] = tile[tx][ty + 8 * i];
}

// ---------------- V -> V^T per (b,h): vt[bh][d][s] = qkv_v[b,s,h,d] ------
__global__ __launch_bounds__(256) void k_vtrans(const u16* __restrict__ qkv,
                                                u16* __restrict__ vt) {
  __shared__ __attribute__((aligned(16))) u16 tile[32][33];
  const int bh = blockIdx.z, b = bh >> 4, h = bh & 15;
  const int s0 = blockIdx.x * 32, d0 = blockIdx.y * 32;
  const int tx = threadIdx.x, ty = threadIdx.y;
#pragma unroll
  for (int i = 0; i < 4; ++i) {
    const int s = s0 + ty + 8 * i;
    tile[ty + 8 * i][tx] = qkv[(b * 2048 + s) * 6144 + 4096 + h * 128 + d0 + tx];
  }
  __syncthreads();
#pragma unroll
  for (int i = 0; i < 4; ++i) {
    const int d = d0 + ty + 8 * i;
    vt[bh * 262144 + d * 2048 + s0 + tx] = tile[tx][ty + 8 * i];
  }
}

// ---------------- RoPE in-place on Q and K sections of qkv (bf16) -------
__global__ __launch_bounds__(256) void k_rope(u16* __restrict__ qkv) {
  const int id = blockIdx.x * 256 + threadIdx.x;  // 8,388,608 threads
  const int j = id & 63;
  const int h = (id >> 6) & 15;
  const int sec = (id >> 10) & 1;
  const int m = id >> 11;  // b*2048+s
  const int s = m & 2047;
  const int base = m * 6144 + sec * 2048 + h * 128 + j;
  const float q0 = bf2f(qkv[base]);
  const float q1 = bf2f(qkv[base + 64]);
  const float inv = exp2f((float)j * -0.20762050593046014f);  // 10000^(-j/64)
  const float ang = (float)s * inv;
  float c, sn;
  sincosf(ang, &sn, &c);  // sincosf(x, SIN*, COS*) — sin FIRST
  qkv[base]      = f2bf(q0 * c - q1 * sn);
  qkv[base + 64] = f2bf(q1 * c + q0 * sn);
}

// ------- GEMM (m97 structure): C[M][N] = A[M][K] * BT[N][K]^T -----------
template <bool A_F32, typename OUT_T>
__global__ __launch_bounds__(256) void k_gemm_lds(const void* __restrict__ Ap, int lda,
                                                  const u16* __restrict__ BT,
                                                  OUT_T* __restrict__ C, int ldc,
                                                  int K) {
  __shared__ __attribute__((aligned(16))) u16 As[128 * 32];
  __shared__ __attribute__((aligned(16))) u16 Bs[128 * 32];
  const int tid = threadIdx.x;
  const int lane = tid & 63, wave = tid >> 6;
  const int lm = lane & 15, quad = lane >> 4;
  const int wm = wave >> 1, wn = wave & 1;
  const int m0 = blockIdx.y * 128, n0 = blockIdx.x * 128;
  const int srow = lane >> 2, scol = (lane & 3) * 8;  // staging map

  const f32x4 fzero = {0.f, 0.f, 0.f, 0.f};
  f32x4 acc[4][4];
#pragma unroll
  for (int i = 0; i < 4; ++i)
#pragma unroll
    for (int j = 0; j < 4; ++j) acc[i][j] = fzero;

  for (int k0 = 0; k0 < K; k0 += 32) {
    __syncthreads();
    if constexpr (A_F32) {
      const float* Af = (const float*)Ap;
#pragma unroll
      for (int i = 0; i < 2; ++i) {
        const int seg = tid + 256 * i;
        const int row = seg >> 2, c8 = (seg & 3) * 8;
        const float4 u = *(const float4*)&Af[(m0 + row) * lda + k0 + c8];
        const float4 w = *(const float4*)&Af[(m0 + row) * lda + k0 + c8 + 4];
        uint4 pk;
        pk.x = (unsigned)f2bf(u.x) | ((unsigned)f2bf(u.y) << 16);
        pk.y = (unsigned)f2bf(u.z) | ((unsigned)f2bf(u.w) << 16);
        pk.z = (unsigned)f2bf(w.x) | ((unsigned)f2bf(w.y) << 16);
        pk.w = (unsigned)f2bf(w.z) | ((unsigned)f2bf(w.w) << 16);
        *(uint4*)&As[row * 32 + c8] = pk;
      }
#pragma unroll
      for (int j = 0; j < 2; ++j) {
        const int rb = wave * 32 + j * 16;
        gl_lds16(&BT[(n0 + rb + srow) * K + k0 + scol], &Bs[rb * 32]);
      }
    } else {
      const u16* Ab = (const u16*)Ap;
#pragma unroll
      for (int j = 0; j < 2; ++j) {
        const int rb = wave * 32 + j * 16;
        gl_lds16(&Ab[(m0 + rb + srow) * lda + k0 + scol], &As[rb * 32]);
        gl_lds16(&BT[(n0 + rb + srow) * K + k0 + scol], &Bs[rb * 32]);
      }
    }
    __syncthreads();  // drains vmcnt (DMA) + lgkmcnt before reads

    s16x8 af[4], bfr[4];
#pragma unroll
    for (int t = 0; t < 4; ++t) {
      af[t]  = *(const s16x8*)&As[(wm * 64 + t * 16 + lm) * 32 + quad * 8];
      bfr[t] = *(const s16x8*)&Bs[(wn * 64 + t * 16 + lm) * 32 + quad * 8];
    }
#pragma unroll
    for (int mt = 0; mt < 4; ++mt)
#pragma unroll
      for (int nt = 0; nt < 4; ++nt)
        acc[mt][nt] = mfma16(af[mt], bfr[nt], acc[mt][nt]);
  }
#pragma unroll
  for (int mt = 0; mt < 4; ++mt)
#pragma unroll
    for (int nt = 0; nt < 4; ++nt)
#pragma unroll
      for (int r = 0; r < 4; ++r) {
        const float v = acc[mt][nt][r];
        const int idx = (m0 + wm * 64 + mt * 16 + quad * 4 + r) * ldc +
                        n0 + wn * 64 + nt * 16 + lm;
        if constexpr (sizeof(OUT_T) == 2) C[idx] = f2bf(v);
        else                              C[idx] = v;
      }
}

// ---------------- causal flash attention, v4 ----------------------------
// 64-key tiles, causal pairing {pair, 31-pair} (33 uniform iters/block),
// DMA double-buffered K/V staging via global_load_lds (no VGPR round-trip,
// no spill), 1 barrier/iter. Unpadded LDS tiles use a global-side XOR
// swizzle (chunk cc = p ^ (row&7)) so b128 reads are bank-conflict-free.
__global__ __launch_bounds__(256) void k_attn(u16* __restrict__ qkv,
                                              const u16* __restrict__ vt) {
  __shared__ __attribute__((aligned(16))) u16 Ks[2][64 * 128];  // 2x16 KB, swizzled
  __shared__ __attribute__((aligned(16))) u16 Vs[2][128 * 64];  // 2x16 KB, swizzled
  __shared__ __attribute__((aligned(16))) u16 Ps[4 * 16 * 72];  //    9 KB
  const int bh = blockIdx.x, pair = blockIdx.y;
  const int b = bh >> 4, h = bh & 15;
  const int tid = threadIdx.x;
  const int lane = tid & 63, wave = tid >> 6;
  const int lm = lane & 15, quad = lane >> 4;
  const int pbase = wave * 1152;
  const int sw = lm & 7;  // read-side swizzle term
  const f32x4 fzero = {0.f, 0.f, 0.f, 0.f};

  const int phase_end = pair;  // it 0..pair: qtile=pair; it pair+1..32: qtile=31-pair

  // async-DMA K/V tile kt0 into buffer `buf` (global-side XOR swizzle)
  auto dma_tile = [&](int kt0, int buf) {
#pragma unroll
    for (int i = 0; i < 4; ++i) {  // K: [64 rows][128 u16], 16 rows/issue
      const int row = i * 16 + wave * 4 + (lane >> 4);
      const int cc = (lane & 15) ^ (row & 7);
      gl_lds16(&qkv[(b * 2048 + kt0 + row) * 6144 + 2048 + h * 128 + cc * 8],
               &Ks[buf][(i * 16 + wave * 4) * 128]);
    }
#pragma unroll
    for (int i = 0; i < 4; ++i) {  // V^T: [128 rows][64 u16], 32 rows/issue
      const int row = i * 32 + wave * 8 + (lane >> 3);
      const int cc = (lane & 7) ^ (row & 7);
      gl_lds16(&vt[bh * 262144 + row * 2048 + kt0 + cc * 8],
               &Vs[buf][(i * 32 + wave * 8) * 64]);
    }
  };

  // ---- prologue: stage tile for it=0 (kt=0) into buf 0 ----
  dma_tile(0, 0);

  // ---- phase-0 state (qtile = pair) ----
  int qtile = pair;
  int qb = qtile * 64;
  int qrow = qb + wave * 16 + lm;
  int qoff = (b * 2048 + qrow) * 6144 + h * 128;
  s16x8 qfrag[4];
#pragma unroll
  for (int c = 0; c < 4; ++c)
    qfrag[c] = *(const s16x8*)&qkv[qoff + c * 32 + quad * 8];
  f32x4 o[8];
#pragma unroll
  for (int dt = 0; dt < 8; ++dt) o[dt] = fzero;
  float m_run = NEG_BIG, l_run = 0.f;

  __syncthreads();  // buf0 DMA drained (vmcnt0 before barrier release)

  for (int it = 0; it < 33; ++it) {
    const int kt0 = (it <= phase_end ? it : it - phase_end - 1) * 64;
    const int buf = it & 1;

    // issue next tile's DMA into the other buffer (latency hidden by compute)
    if (it < 32) {
      const int nkt = (it + 1 <= phase_end ? it + 1 : it - phase_end) * 64;
      dma_tile(nkt, buf ^ 1);
    }

    // ---- S^T = K * Q^T on buf ----
    f32x4 sa[4];
#pragma unroll
    for (int ss = 0; ss < 4; ++ss) sa[ss] = fzero;
#pragma unroll
    for (int ss = 0; ss < 4; ++ss)
#pragma unroll
      for (int c = 0; c < 4; ++c) {
        const int ccs = (c * 4 + quad) ^ sw;
        s16x8 a = *(const s16x8*)&Ks[buf][(ss * 16 + lm) * 128 + ccs * 8];
        sa[ss] = mfma16(a, qfrag[c], sa[ss]);
      }

    // ---- scale + causal mask + online softmax (per column q = lm) ----
    float p[4][4];
    float vmax = NEG_BIG;
#pragma unroll
    for (int ss = 0; ss < 4; ++ss)
#pragma unroll
      for (int r = 0; r < 4; ++r) {
        const int kg = kt0 + ss * 16 + quad * 4 + r;
        float v = sa[ss][r] * ATTN_SCALE;
        if (kg > qrow) v = NEG_BIG;
        p[ss][r] = v;
        vmax = fmaxf(vmax, v);
      }
    vmax = fmaxf(vmax, __shfl_xor(vmax, 16, 64));
    vmax = fmaxf(vmax, __shfl_xor(vmax, 32, 64));
    const float m_new = fmaxf(m_run, vmax);
    const float alpha = __expf(m_run - m_new);
    float rsum = 0.f;
#pragma unroll
    for (int ss = 0; ss < 4; ++ss)
#pragma unroll
      for (int r = 0; r < 4; ++r) {
        p[ss][r] = __expf(p[ss][r] - m_new);  // masked: exp(-huge) = 0
        rsum += p[ss][r];
      }
    rsum += __shfl_xor(rsum, 16, 64);
    rsum += __shfl_xor(rsum, 32, 64);
    l_run = l_run * alpha + rsum;
    m_run = m_new;
#pragma unroll
    for (int dt = 0; dt < 8; ++dt) o[dt] *= alpha;

    // ---- P -> wave-private LDS bounce (intra-wave ordering, no barrier) --
#pragma unroll
    for (int ss = 0; ss < 4; ++ss)
#pragma unroll
      for (int r = 0; r < 4; ++r)
        Ps[pbase + lm * 72 + ss * 16 + quad * 4 + r] = f2bf(p[ss][r]);
    const s16x8 pv0 = *(const s16x8*)&Ps[pbase + lm * 72 + quad * 8];
    const s16x8 pv1 = *(const s16x8*)&Ps[pbase + lm * 72 + 32 + quad * 8];

    // ---- O^T += V^T * P^T over the two 32-key halves ----
#pragma unroll
    for (int dt = 0; dt < 8; ++dt) {
      const int c0 = (quad ^ sw) * 8, c1 = ((4 + quad) ^ sw) * 8;
      s16x8 a0 = *(const s16x8*)&Vs[buf][(dt * 16 + lm) * 64 + c0];
      s16x8 a1 = *(const s16x8*)&Vs[buf][(dt * 16 + lm) * 64 + c1];
      o[dt] = mfma16(a1, pv1, mfma16(a0, pv0, o[dt]));
    }

    // ---- phase boundary: write phase-0 output, reset for phase 1 ----
    if (it == phase_end) {
      const float inv_l = 1.0f / l_run;
#pragma unroll
      for (int dt = 0; dt < 8; ++dt)
#pragma unroll
        for (int r = 0; r < 4; ++r)
          qkv[qoff + dt * 16 + quad * 4 + r] = f2bf(o[dt][r] * inv_l);
      qtile = 31 - pair;
      qb = qtile * 64;
      qrow = qb + wave * 16 + lm;
      qoff = (b * 2048 + qrow) * 6144 + h * 128;
#pragma unroll
      for (int c = 0; c < 4; ++c)
        qfrag[c] = *(const s16x8*)&qkv[qoff + c * 32 + quad * 8];
#pragma unroll
      for (int dt = 0; dt < 8; ++dt) o[dt] = fzero;
      m_run = NEG_BIG; l_run = 0.f;
    }

    // single barrier: drains this iter's DMA (vmcnt0) + guards buf reuse
    if (it < 32) __syncthreads();
  }

  // ---- phase-1 epilogue ----
  const float inv_l = 1.0f / l_run;
#pragma unroll
  for (int dt = 0; dt < 8; ++dt)
#pragma unroll
    for (int r = 0; r < 4; ++r)
      qkv[qoff + dt * 16 + quad * 4 + r] = f2bf(o[dt][r] * inv_l);
}

// ---------------- host launcher ----------------------------------------
extern "C" void kernel_launch(void* const* d_in, const int* in_sizes, int n_in,
                              void* d_out, int out_size, void* d_ws, size_t ws_size,
                              hipStream_t stream) {
  const float* hidden = (const float*)d_in[0];  // [4096][2048] fp32
  const float* w_qkv  = (const float*)d_in[1];  // [2048][6144] fp32
  const float* w_o    = (const float*)d_in[2];  // [2048][2048] fp32
  float* out = (float*)d_out;                   // [4096][2048] fp32
  u16* ws = (u16*)d_ws;

  u16* qkv   = ws;
  u16* wqkvT = ws + 25165824;
  u16* vt    = ws + 25165824;
  u16* woT   = ws + 33554432;
  u16* hb    = ws + 37748736;
  const bool fast = ws_size >= (size_t)46137344 * 2;

  dim3 tb(32, 8);
  k_transpose_cast<<<dim3(192, 64), tb, 0, stream>>>(w_qkv, wqkvT, 2048, 6144);
  if (fast) {
    k_cast<<<8192, 256, 0, stream>>>(hidden, hb, 2097152);
    k_gemm_lds<false, u16><<<dim3(48, 32), 256, 0, stream>>>(hb, 2048, wqkvT,
                                                             qkv, 6144, 2048);
  } else {
    k_gemm_lds<true, u16><<<dim3(48, 32), 256, 0, stream>>>(hidden, 2048, wqkvT,
                                                            qkv, 6144, 2048);
  }
  k_rope<<<32768, 256, 0, stream>>>(qkv);
  k_vtrans<<<dim3(64, 4, 32), tb, 0, stream>>>(qkv, vt);
  k_transpose_cast<<<dim3(64, 64), tb, 0, stream>>>(w_o, woT, 2048, 2048);
  k_attn<<<dim3(32, 16), 256, 0, stream>>>(qkv, vt);  // x=bh (XCD locality)
  k_gemm_lds<false, float><<<dim3(16, 32), 256, 0, stream>>>(qkv, 6144, woT,
                                                             out, 2048, 2048);
}